// Round 9
// baseline (54.434 us; speedup 1.0000x reference)
//
#include <hip/hip_runtime.h>
#include <hip/hip_bf16.h>

// Problem constants: B=16384, N=20, D=64, R=3, K=64
#define BB   16384
#define NN   20
#define NREL 3

typedef __attribute__((ext_vector_type(8))) short  short8;
typedef __attribute__((ext_vector_type(4))) float  f32x4;

__device__ __forceinline__ float lo16(unsigned int u) {
    union { unsigned int x; float f; } c; c.x = u << 16; return c.f;
}
__device__ __forceinline__ float hi16(unsigned int u) {
    union { unsigned int x; float f; } c; c.x = u & 0xFFFF0000u; return c.f;
}

// f32 -> bf16 (RNE), returned as raw ushort
__device__ __forceinline__ unsigned short f2bu(float f) {
    union { float f; unsigned int u; } x;
    x.f = f;
    unsigned int r = x.u + 0x7FFFu + ((x.u >> 16) & 1u);
    return (unsigned short)(r >> 16);
}

// ---------------------------------------------------------------------------
// K1: McatT[r*128+e][d] = sum_k w_uir[r][d][k] * w_aor[r][e][k]   (bf16 out)
//     cvec[r*128+e]     = sum_k r_vec[r][k]   * w_aor[r][e][k]    (f32 out)
// ---------------------------------------------------------------------------
__global__ __launch_bounds__(256) void k_precompute(
    const float* __restrict__ w_uir,
    const float* __restrict__ w_aor,
    const float* __restrict__ r_vec,
    unsigned short* __restrict__ McatT,   // [384][128] bf16 bits
    float* __restrict__ cvec)             // [384]
{
    int idx = blockIdx.x * 256 + threadIdx.x;
    if (idx < NREL * 128 * 128) {
        int d = idx & 127;
        int e = (idx >> 7) & 127;
        int r = idx >> 14;
        const float4* pu = reinterpret_cast<const float4*>(w_uir + (r * 128 + d) * 64);
        const float4* pa = reinterpret_cast<const float4*>(w_aor + (r * 128 + e) * 64);
        float acc = 0.f;
        #pragma unroll
        for (int k = 0; k < 16; ++k) {
            float4 a = pu[k], b = pa[k];
            acc += a.x * b.x + a.y * b.y + a.z * b.z + a.w * b.w;
        }
        McatT[(r * 128 + e) * 128 + d] = f2bu(acc);
    } else if (idx < NREL * 128 * 128 + NREL * 128) {
        int j = idx - NREL * 128 * 128;
        int r = j >> 7, e = j & 127;
        const float4* pr = reinterpret_cast<const float4*>(r_vec + r * 64);
        const float4* pa = reinterpret_cast<const float4*>(w_aor + (r * 128 + e) * 64);
        float acc = 0.f;
        #pragma unroll
        for (int k = 0; k < 16; ++k) {
            float4 a = pr[k], b = pa[k];
            acc += a.x * b.x + a.y * b.y + a.z * b.z + a.w * b.w;
        }
        cvec[j] = acc;
    }
}

// ---------------------------------------------------------------------------
// K2: v'[b][j] = sum_d ui_in[b][d] * McatT[j][d] + cvec[j]
//     GEMM M=16384 N=384 K=128, bf16 MFMA 16x16x32, 64x64 block tiles.
// ---------------------------------------------------------------------------
__global__ __launch_bounds__(256) void k_gemm(
    const float* __restrict__ u_emb,
    const float* __restrict__ i_emb,
    const unsigned short* __restrict__ McatT,  // [384][128] bf16 bits
    const float* __restrict__ cvec,            // [384]
    unsigned short* __restrict__ vp)           // [16384][384] bf16 bits
{
    __shared__ unsigned short Atile[64][136];  // +8 pad
    const int t = threadIdx.x;
    const int bm = blockIdx.x & 255;   // 256 M tiles
    const int bn = blockIdx.x >> 8;    // 6 N tiles
    const int Mbase = bm * 64;
    const int Nbase = bn * 64;

    #pragma unroll
    for (int it = 0; it < 8; ++it) {
        int idx  = it * 256 + t;       // 0..2047, each covers 4 floats
        int row  = idx >> 5;
        int colg = idx & 31;
        const float* src = (colg < 16)
            ? (u_emb + (Mbase + row) * 64 + colg * 4)
            : (i_emb + (Mbase + row) * 64 + (colg - 16) * 4);
        float4 v = *reinterpret_cast<const float4*>(src);
        ushort4 h;
        h.x = f2bu(v.x); h.y = f2bu(v.y); h.z = f2bu(v.z); h.w = f2bu(v.w);
        *reinterpret_cast<ushort4*>(&Atile[row][colg * 4]) = h;
    }
    __syncthreads();

    const int w    = t >> 6;
    const int lane = t & 63;
    const int lr   = lane & 15;
    const int lk   = (lane >> 4) * 8;

    short8 afrag[4];
    #pragma unroll
    for (int kk = 0; kk < 4; ++kk)
        afrag[kk] = *reinterpret_cast<const short8*>(&Atile[w * 16 + lr][kk * 32 + lk]);

    #pragma unroll
    for (int nt = 0; nt < 4; ++nt) {
        f32x4 acc = {0.f, 0.f, 0.f, 0.f};
        int col = Nbase + nt * 16 + lr;
        #pragma unroll
        for (int kk = 0; kk < 4; ++kk) {
            short8 bfrag = *reinterpret_cast<const short8*>(McatT + col * 128 + kk * 32 + lk);
            acc = __builtin_amdgcn_mfma_f32_16x16x32_bf16(afrag[kk], bfrag, acc, 0, 0, 0);
        }
        float cb = cvec[col];
        #pragma unroll
        for (int reg = 0; reg < 4; ++reg) {
            int grow = Mbase + w * 16 + (lane >> 4) * 4 + reg;
            vp[grow * 384 + col] = f2bu(acc[reg] + cb);
        }
    }
}

// ---------------------------------------------------------------------------
// K3: pred[t] = sum_e ao_in[t][e] * v'[b][s[t]*128 + e],  ao_in = [a|o]
//     Looped double-buffered DMA pipeline (the minimum 2-phase schedule):
//     STAGE(it+1) -> CONSUME(it) -> __syncthreads(). All bulk traffic via
//     global_load_lds (no VGPR destinations, regalloc-proof). Memory queue
//     stays non-empty continuously: stage of slice it+1 drains while slice
//     it is consumed; barrier drain is the landing guarantee. 2 blocks/CU
//     stagger each other. Slice = 2 b's = 40 triples = 21.9 KB.
// ---------------------------------------------------------------------------
#define K3_BLOCKS 512
#define K3_ITERS  16
#define K3_TPS    40          // triples per slice (2 b's)

#define SL_A   0              // 10240 B  (40 triples x 256 B)
#define SL_O   10240          // 10240 B
#define SL_VP  20480          // 1536 B   (2 b x 3 rel x 256 B)
#define SL_S   22016          // 160 B
#define SL_SZ  22272          // slice stride (16B aligned)

__device__ __forceinline__ void k3_stage(
    const float* __restrict__ a_emb, const float* __restrict__ o_emb,
    const int* __restrict__ s, const unsigned short* __restrict__ vp,
    char* L, int sidx, int wv, int lane)
{
    const size_t t0s = (size_t)sidx * K3_TPS;

    // s first: its waitcnt then only counts the newer DMAs (vmcnt(N), no drain)
    int sval = 0;
    if (wv == 2 && lane < K3_TPS) sval = s[t0s + lane];

    const char* asrc = (const char*)(a_emb + t0s * 64);
    const char* osrc = (const char*)(o_emb + t0s * 64);
    const char* vsrc = (const char*)(vp + (size_t)sidx * (2 * 3 * 128));

    if (wv < 2) {
        #pragma unroll
        for (int i = 0; i < 5; ++i) {
            int seg = i * 2 + wv;
            __builtin_amdgcn_global_load_lds(
                (const unsigned int*)(asrc + seg * 1024 + (size_t)lane * 16),
                (unsigned int*)(L + SL_A + seg * 1024), 16, 0, 0);
        }
    } else {
        #pragma unroll
        for (int i = 0; i < 5; ++i) {
            int seg = i * 2 + (wv & 1);
            __builtin_amdgcn_global_load_lds(
                (const unsigned int*)(osrc + seg * 1024 + (size_t)lane * 16),
                (unsigned int*)(L + SL_O + seg * 1024), 16, 0, 0);
        }
    }
    if (wv == 3) {
        __builtin_amdgcn_global_load_lds(
            (const unsigned int*)(vsrc + (size_t)lane * 16),
            (unsigned int*)(L + SL_VP), 16, 0, 0);
        if (lane < 32)
            __builtin_amdgcn_global_load_lds(
                (const unsigned int*)(vsrc + 1024 + (size_t)lane * 16),
                (unsigned int*)(L + SL_VP + 1024), 16, 0, 0);
    }
    if (wv == 2 && lane < K3_TPS)
        *(int*)(L + SL_S + lane * 4) = sval;
}

__device__ __forceinline__ void k3_consume(
    const char* L, int sidx, int g, int sub, float* __restrict__ out)
{
    const size_t t0s = (size_t)sidx * K3_TPS;
    #pragma unroll
    for (int p = 0; p < 3; ++p) {
        const int ltrip = p * 16 + g;
        if (p < 2 || g < 8) {                       // 40 triples: 16+16+8
            const int bl  = ltrip / NN;             // 0 or 1
            const int sv  = *(const int*)(L + SL_S + ltrip * 4);
            const int row = bl * 3 + sv;
            float4 af = *(const float4*)(L + SL_A + ltrip * 256 + sub * 16);
            float4 of = *(const float4*)(L + SL_O + ltrip * 256 + sub * 16);
            uint2  wa = *(const uint2*)(L + SL_VP + row * 256 + sub * 8);
            uint2  wo = *(const uint2*)(L + SL_VP + row * 256 + 128 + sub * 8);
            float r = af.x * lo16(wa.x) + af.y * hi16(wa.x)
                    + af.z * lo16(wa.y) + af.w * hi16(wa.y)
                    + of.x * lo16(wo.x) + of.y * hi16(wo.x)
                    + of.z * lo16(wo.y) + of.w * hi16(wo.y);
            r += __shfl_xor(r, 1, 64);
            r += __shfl_xor(r, 2, 64);
            r += __shfl_xor(r, 4, 64);
            r += __shfl_xor(r, 8, 64);
            if (sub == 0) out[t0s + ltrip] = r;
        }
    }
}

__global__ __launch_bounds__(256) void k_pred(
    const float* __restrict__ a_emb,
    const float* __restrict__ o_emb,
    const int* __restrict__ s,
    const unsigned short* __restrict__ vp,
    float* __restrict__ out)
{
    __shared__ __align__(16) char lds[2 * SL_SZ];   // 44544 B

    const int tid  = threadIdx.x;
    const int wv   = tid >> 6;
    const int lane = tid & 63;
    const int bid  = blockIdx.x;
    const int g    = tid >> 4;
    const int sub  = tid & 15;

    const int sbase = bid * K3_ITERS;

    k3_stage(a_emb, o_emb, s, vp, lds, sbase, wv, lane);
    __syncthreads();                                 // slice 0 landed

    for (int it = 0; it < K3_ITERS; ++it) {
        if (it + 1 < K3_ITERS)
            k3_stage(a_emb, o_emb, s, vp, lds + ((it + 1) & 1) * SL_SZ,
                     sbase + it + 1, wv, lane);      // flies during consume
        k3_consume(lds + (it & 1) * SL_SZ, sbase + it, g, sub, out);
        __syncthreads();                             // drain: slice it+1 landed;
                                                     // all waves done with buf(it)
    }
}

// ---------------------------------------------------------------------------
extern "C" void kernel_launch(void* const* d_in, const int* in_sizes, int n_in,
                              void* d_out, int out_size, void* d_ws, size_t ws_size,
                              hipStream_t stream) {
    const float* u_emb = (const float*)d_in[0];
    const float* i_emb = (const float*)d_in[1];
    const float* a_emb = (const float*)d_in[2];
    const float* o_emb = (const float*)d_in[3];
    const int*   s     = (const int*)d_in[4];
    const float* w_uir = (const float*)d_in[5];
    const float* w_aor = (const float*)d_in[6];
    const float* r_vec = (const float*)d_in[7];
    float* out = (float*)d_out;

    char* ws = (char*)d_ws;
    unsigned short* McatT = (unsigned short*)ws;              // 98304 B
    float*          cvec  = (float*)(ws + 98304);             // 1536 B
    unsigned short* vp    = (unsigned short*)(ws + 102400);   // 12.58 MB

    k_precompute<<<194, 256, 0, stream>>>(w_uir, w_aor, r_vec, McatT, cvec);
    k_gemm<<<1536, 256, 0, stream>>>(u_emb, i_emb, McatT, cvec, vp);
    k_pred<<<K3_BLOCKS, 256, 0, stream>>>(a_emb, o_emb, s, vp, out);
}